// Round 1
// baseline (462.046 us; speedup 1.0000x reference)
//
#include <hip/hip_runtime.h>

#define B_ 16
#define T_ 2048
#define D_ 768
#define A_ 5
#define D4_ 192      // D/4 float4s per row
#define NC_ 32       // t-chunks for partial-sum kernels
#define TC_ 64       // T_/NC_

__device__ inline float wave_max(float v){
  #pragma unroll
  for(int off=32; off>0; off>>=1) v = fmaxf(v, __shfl_down(v, off, 64));
  return v;
}
__device__ inline float wave_sum(float v){
  #pragma unroll
  for(int off=32; off>0; off>>=1) v += __shfl_down(v, off, 64);
  return v;
}

// K1a: partial masked sums of q over t-chunks. grid (B_, NC_), block 192
__global__ void k1a_agent_partial(const float* __restrict__ q,
                                  const int* __restrict__ mask,
                                  float* __restrict__ partial_q){
  const int b = blockIdx.x, c = blockIdx.y, tid = threadIdx.x;
  const int t0 = c * TC_;
  __shared__ int ml[TC_];
  if(tid < TC_) ml[tid] = mask[b*T_ + t0 + tid];
  __syncthreads();
  const float4* q4 = (const float4*)q + ((size_t)b*T_ + t0)*D4_;
  float4 acc = {0.f,0.f,0.f,0.f};
  #pragma unroll 4
  for(int i=0;i<TC_;i++){
    if(ml[i]){                       // wave-uniform branch: skips whole 3KB rows
      float4 x = q4[(size_t)i*D4_ + tid];
      acc.x+=x.x; acc.y+=x.y; acc.z+=x.z; acc.w+=x.w;
    }
  }
  ((float4*)partial_q)[((size_t)b*NC_ + c)*D4_ + tid] = acc;
}

// K1b: reduce partials, divide by T. grid 12, block 256 (3072 float4 outputs)
__global__ void k1b_agent_reduce(const float* __restrict__ partial_q,
                                 float* __restrict__ agentvec){
  const int idx = blockIdx.x*256 + threadIdx.x;   // 0..3071
  const int b = idx / D4_, d4 = idx % D4_;
  const float4* p4 = (const float4*)partial_q;
  float4 acc = {0.f,0.f,0.f,0.f};
  #pragma unroll 8
  for(int c=0;c<NC_;c++){
    float4 x = p4[((size_t)b*NC_ + c)*D4_ + d4];
    acc.x+=x.x; acc.y+=x.y; acc.z+=x.z; acc.w+=x.w;
  }
  const float sc = 1.0f / (float)T_;
  acc.x*=sc; acc.y*=sc; acc.z*=sc; acc.w*=sc;
  ((float4*)agentvec)[idx] = acc;
}

// K2: s[b,t] = dot(agentvec[b], k[b,t]). grid (B_, 64), block 256 (4 waves, 8 t each)
__global__ void k2_scores(const float* __restrict__ k,
                          const float* __restrict__ agentvec,
                          float* __restrict__ s){
  const int b = blockIdx.x, tid = threadIdx.x;
  const int t0 = blockIdx.y * 32;
  __shared__ float4 avs[D4_];
  if(tid < D4_) avs[tid] = ((const float4*)agentvec)[b*D4_ + tid];
  __syncthreads();
  const int wave = tid >> 6, lane = tid & 63;
  const float4* k4 = (const float4*)k;
  for(int i=0;i<8;i++){
    const int t = t0 + wave*8 + i;
    const float4* kr = k4 + ((size_t)b*T_ + t)*D4_;
    float sum = 0.f;
    #pragma unroll
    for(int j=0;j<3;j++){
      float4 kv = kr[lane + 64*j];
      float4 av = avs[lane + 64*j];
      sum += kv.x*av.x + kv.y*av.y + kv.z*av.z + kv.w*av.w;
    }
    sum = wave_sum(sum);
    if(lane == 0) s[b*T_ + t] = sum;
  }
}

// K3: w[b,a,:] = softmax_t(s[b,:] + b1[a,:]). grid (B_, A_), block 256
__global__ void k3_softmax_w(const float* __restrict__ s,
                             const float* __restrict__ b1,
                             float* __restrict__ w){
  const int b = blockIdx.x, a = blockIdx.y, tid = threadIdx.x;
  const float* srow = s + b*T_;
  const float* brow = b1 + a*T_;
  float vals[8];
  float mx = -1e30f;
  #pragma unroll
  for(int i=0;i<8;i++){
    const int t = tid + i*256;
    float x = srow[t] + brow[t];
    vals[i] = x;
    mx = fmaxf(mx, x);
  }
  __shared__ float redm[4], reds[4];
  const int wave = tid >> 6, lane = tid & 63;
  float wm = wave_max(mx);
  if(lane==0) redm[wave] = wm;
  __syncthreads();
  const float bm = fmaxf(fmaxf(redm[0],redm[1]), fmaxf(redm[2],redm[3]));
  float sum = 0.f;
  #pragma unroll
  for(int i=0;i<8;i++){
    float e = __expf(vals[i] - bm);
    vals[i] = e;
    sum += e;
  }
  float wsu = wave_sum(sum);
  if(lane==0) reds[wave] = wsu;
  __syncthreads();
  const float inv = 1.0f / (reds[0]+reds[1]+reds[2]+reds[3]);
  float* wrow = w + ((size_t)b*A_ + a)*T_;
  #pragma unroll
  for(int i=0;i<8;i++) wrow[tid + i*256] = vals[i]*inv;
}

// K3b: p[t,:] = softmax_a(b2[t,:]). grid 8, block 256
__global__ void k3b_softmax_p(const float* __restrict__ b2,
                              float* __restrict__ p){
  const int t = blockIdx.x*256 + threadIdx.x;
  float x[A_];
  float mx = -1e30f;
  #pragma unroll
  for(int a=0;a<A_;a++){ x[a] = b2[t*A_ + a]; mx = fmaxf(mx, x[a]); }
  float sum = 0.f;
  #pragma unroll
  for(int a=0;a<A_;a++){ x[a] = __expf(x[a]-mx); sum += x[a]; }
  const float inv = 1.0f / sum;
  #pragma unroll
  for(int a=0;a<A_;a++) p[t*A_ + a] = x[a]*inv;
}

// K4a: partial agent_v sums over t-chunks. grid (B_, NC_), block 192
__global__ void k4a_agentv_partial(const float* __restrict__ v,
                                   const float* __restrict__ w,
                                   float* __restrict__ partial_av){
  const int b = blockIdx.x, c = blockIdx.y, tid = threadIdx.x;
  const int t0 = c * TC_;
  __shared__ float wl[A_][TC_];
  for(int i=tid; i<A_*TC_; i+=192){
    const int a = i >> 6, tt = i & 63;
    wl[a][tt] = w[((size_t)b*A_ + a)*T_ + t0 + tt];
  }
  __syncthreads();
  const float4* v4 = (const float4*)v + ((size_t)b*T_ + t0)*D4_;
  float4 acc0={0,0,0,0}, acc1={0,0,0,0}, acc2={0,0,0,0}, acc3={0,0,0,0}, acc4={0,0,0,0};
  #pragma unroll 4
  for(int i=0;i<TC_;i++){
    float4 vv = v4[(size_t)i*D4_ + tid];
    float w0=wl[0][i], w1=wl[1][i], w2=wl[2][i], w3=wl[3][i], w4=wl[4][i];
    acc0.x+=w0*vv.x; acc0.y+=w0*vv.y; acc0.z+=w0*vv.z; acc0.w+=w0*vv.w;
    acc1.x+=w1*vv.x; acc1.y+=w1*vv.y; acc1.z+=w1*vv.z; acc1.w+=w1*vv.w;
    acc2.x+=w2*vv.x; acc2.y+=w2*vv.y; acc2.z+=w2*vv.z; acc2.w+=w2*vv.w;
    acc3.x+=w3*vv.x; acc3.y+=w3*vv.y; acc3.z+=w3*vv.z; acc3.w+=w3*vv.w;
    acc4.x+=w4*vv.x; acc4.y+=w4*vv.y; acc4.z+=w4*vv.z; acc4.w+=w4*vv.w;
  }
  float4* pav = (float4*)partial_av + (((size_t)b*NC_ + c)*A_)*D4_;
  pav[0*D4_ + tid] = acc0;
  pav[1*D4_ + tid] = acc1;
  pav[2*D4_ + tid] = acc2;
  pav[3*D4_ + tid] = acc3;
  pav[4*D4_ + tid] = acc4;
}

// K4b: reduce agent_v partials. grid 60, block 256 (15360 float4 outputs)
__global__ void k4b_agentv_reduce(const float* __restrict__ partial_av,
                                  float* __restrict__ agent_v){
  const int idx = blockIdx.x*256 + threadIdx.x;   // 0..15359
  const int b = idx / (A_*D4_);
  const int r = idx % (A_*D4_);
  const float4* p4 = (const float4*)partial_av;
  float4 acc = {0.f,0.f,0.f,0.f};
  #pragma unroll 8
  for(int c=0;c<NC_;c++){
    float4 x = p4[((size_t)b*NC_ + c)*(A_*D4_) + r];
    acc.x+=x.x; acc.y+=x.y; acc.z+=x.z; acc.w+=x.w;
  }
  ((float4*)agent_v)[idx] = acc;
}

// K5: x[b,t,:] = sum_a p[t,a]*agent_v[b,a,:]. grid (B_, T_/16), block 256
__global__ void k5_final(const float* __restrict__ agent_v,
                         const float* __restrict__ p,
                         float* __restrict__ out){
  const int b = blockIdx.x, tid = threadIdx.x;
  const int t0 = blockIdx.y * 16;
  __shared__ float4 avs[A_*D4_];   // 15 KB
  __shared__ float pl[16*A_];
  const float4* av4 = (const float4*)agent_v + (size_t)b*A_*D4_;
  for(int i=tid; i<A_*D4_; i+=256) avs[i] = av4[i];
  if(tid < 16*A_) pl[tid] = p[t0*A_ + tid];
  __syncthreads();
  float4* out4 = (float4*)out + ((size_t)b*T_ + t0)*D4_;
  #pragma unroll
  for(int it=0; it<12; it++){
    const int idx = it*256 + tid;           // 0..3071 = 16 rows * 192 float4
    const int tl = idx / D4_;
    const int d4 = idx - tl*D4_;
    float4 o = {0.f,0.f,0.f,0.f};
    #pragma unroll
    for(int a=0;a<A_;a++){
      const float pw = pl[tl*A_ + a];
      float4 av = avs[a*D4_ + d4];
      o.x += pw*av.x; o.y += pw*av.y; o.z += pw*av.z; o.w += pw*av.w;
    }
    out4[(size_t)tl*D4_ + d4] = o;
  }
}

extern "C" void kernel_launch(void* const* d_in, const int* in_sizes, int n_in,
                              void* d_out, int out_size, void* d_ws, size_t ws_size,
                              hipStream_t stream) {
  const float* qkv  = (const float*)d_in[0];
  const int*   mask = (const int*)d_in[1];
  const float* b1   = (const float*)d_in[2];
  const float* b2   = (const float*)d_in[3];
  float* out = (float*)d_out;

  const size_t BTD = (size_t)B_*T_*D_;
  const float* q = qkv;
  const float* k = qkv + BTD;
  const float* v = qkv + 2*BTD;

  // workspace layout (floats) — all 16B-aligned
  float* wsf        = (float*)d_ws;
  float* partial_q  = wsf;                                   // B*NC*D      = 393216
  float* agentvec   = partial_q + (size_t)B_*NC_*D_;         // B*D         = 12288
  float* s_buf      = agentvec  + (size_t)B_*D_;             // B*T         = 32768
  float* w_buf      = s_buf     + (size_t)B_*T_;             // B*A*T       = 163840
  float* p_buf      = w_buf     + (size_t)B_*A_*T_;          // T*A         = 10240
  float* partial_av = p_buf     + (size_t)T_*A_;             // B*NC*A*D    = 1966080
  float* agent_v    = partial_av+ (size_t)B_*NC_*A_*D_;      // B*A*D       = 61440

  k1a_agent_partial<<<dim3(B_, NC_), 192, 0, stream>>>(q, mask, partial_q);
  k1b_agent_reduce <<<12, 256, 0, stream>>>(partial_q, agentvec);
  k2_scores        <<<dim3(B_, 64), 256, 0, stream>>>(k, agentvec, s_buf);
  k3_softmax_w     <<<dim3(B_, A_), 256, 0, stream>>>(s_buf, b1, w_buf);
  k3b_softmax_p    <<<8, 256, 0, stream>>>(b2, p_buf);
  k4a_agentv_partial<<<dim3(B_, NC_), 192, 0, stream>>>(v, w_buf, partial_av);
  k4b_agentv_reduce<<<60, 256, 0, stream>>>(partial_av, agent_v);
  k5_final         <<<dim3(B_, T_/16), 256, 0, stream>>>(agent_v, p_buf, out);
}